// Round 10
// baseline (81.690 us; speedup 1.0000x reference)
//
#include <hip/hip_runtime.h>

#define H_ 512
#define N_ 32
#define B_ 4
#define L_ 2048
#define LC 128
#define NC 16   // L_/NC

typedef _Float16 f16x8 __attribute__((ext_vector_type(8)));
typedef float f32x4 __attribute__((ext_vector_type(4)));
typedef float f32x2 __attribute__((ext_vector_type(2)));

__device__ inline unsigned short f2h(float f) {
  _Float16 h = (_Float16)f;   // RNE
  return __builtin_bit_cast(unsigned short, h);
}

// ---- packed fp32 helpers (VOP3P, 2x rate) ----
__device__ inline f32x2 pk_fma(f32x2 a, f32x2 b, f32x2 c) {
  f32x2 d;
  asm("v_pk_fma_f32 %0, %1, %2, %3" : "=v"(d) : "v"(a), "v"(b), "v"(c));
  return d;
}
// lo = a.lo*(-x.hi) + c.lo ; hi = a.hi*x.lo + c.hi   (complex cross-term)
__device__ inline f32x2 pk_fma_swapneg(f32x2 a, f32x2 x, f32x2 c) {
  f32x2 d;
  asm("v_pk_fma_f32 %0, %1, %2, %3 op_sel:[0,1,0] op_sel_hi:[1,0,1] neg_lo:[0,1,0]"
      : "=v"(d) : "v"(a), "v"(x), "v"(c));
  return d;
}
__device__ inline f32x2 pk_mul(f32x2 a, f32x2 b) {
  f32x2 d;
  asm("v_pk_mul_f32 %0, %1, %2" : "=v"(d) : "v"(a), "v"(b));
  return d;
}

#define GLD_LDS16(gsrc, ldst)                                                        \
  __builtin_amdgcn_global_load_lds(                                                  \
      (const __attribute__((address_space(1))) unsigned int*)(gsrc),                 \
      (__attribute__((address_space(3))) unsigned int*)(ldst), 16, 0, 0)

// Inline per-thread discretization: lane ln owns n = ln*4..ln*4+3 of row h.
// Produces packed constants: Ar2=(ar,ar) Ai2=(ai,ai) Bd2=(br,bi) Cc2=(cr,ci).
#define DISCRETIZE_PK(h, ln)                                                         \
  {                                                                                  \
    float dtv = expf(log_dt[(h)]);                                                   \
    _Pragma("unroll")                                                                \
    for (int i = 0; i < 4; ++i) {                                                    \
      int n = (ln) * 4 + i;                                                          \
      int idx = ((h) << 5) + n;                                                      \
      float ar = -expf(log_A_real[idx]);                                             \
      float ai = A_imag[idx];                                                        \
      float dr = 0.5f * dtv * ar, di = 0.5f * dtv * ai;                              \
      float omr = 1.0f - dr;                                                         \
      float inv = 1.0f / (omr * omr + di * di);                                      \
      float adr = (1.0f - dr * dr - di * di) * inv;                                  \
      float adi = 2.0f * di * inv;                                                   \
      float br = B_ri[2 * n], bi = B_ri[2 * n + 1];                                  \
      Ar2[i] = (f32x2){adr, adr};                                                    \
      Ai2[i] = (f32x2){adi, adi};                                                    \
      Bd2[i] = (f32x2){dtv * (br * omr - bi * di) * inv,                             \
                       dtv * (br * di + bi * omr) * inv};                            \
      float2 c = ((const float2*)C_ri)[idx];                                         \
      Cc2[i] = (f32x2){c.x, c.y};                                                    \
    }                                                                                \
  }

// ---------------- scan1: W-transpose prologue + zero-init local chunk scans ----------------
// grid (NC-1, 16, B_) x 256 thr. Block = (chunk c, h-tile ht, batch b).
__global__ __launch_bounds__(256) void scan1_k(
    const float* __restrict__ x,
    const float* __restrict__ log_dt,
    const float* __restrict__ log_A_real,
    const float* __restrict__ A_imag,
    const float* __restrict__ B_ri,
    const float* __restrict__ C_ri,
    const float* __restrict__ W1,
    const float* __restrict__ W2,
    unsigned short* __restrict__ WT1,
    unsigned short* __restrict__ WT2,
    float2* __restrict__ xend) {
  __shared__ float ut[LC][36];
  int c = blockIdx.x, ht = blockIdx.y, b = blockIdx.z;
  int tid = threadIdx.x;

  // ---- W transpose prologue: contiguous flat id over the 960-block grid ----
  int flat = (b * 16 + ht) * (NC - 1) + c;   // 0..959
  if (flat < 512) {
    float(*tile)[33] = (float(*)[33]) & ut[0][0];   // 4224 B, fits in ut
    const float* W = (flat >> 8) ? W2 : W1;
    unsigned short* WT = (flat >> 8) ? WT2 : WT1;
    int rem = flat & 255;
    int k0 = (rem & 15) << 5, j0 = (rem >> 4) << 5;
    int tx = tid & 31, ty = tid >> 5;
#pragma unroll
    for (int i = 0; i < 32; i += 8)
      tile[ty + i][tx] = W[(size_t)(k0 + ty + i) * H_ + j0 + tx];
    __syncthreads();
#pragma unroll
    for (int i = 0; i < 32; i += 8)
      WT[(size_t)(j0 + ty + i) * H_ + k0 + tx] = f2h(tile[tx][ty + i]);
    __syncthreads();
  }

  // ---- stage u tile [128 t][32 h], coalesced ----
#pragma unroll
  for (int i = 0; i < 4; ++i) {
    int r = i * 32 + (tid >> 3);
    int q = tid & 7;
    float4 v = *(const float4*)(x + ((size_t)(b * L_ + c * LC + r) * H_) + ht * 32 + q * 4);
    *(float4*)&ut[r][q * 4] = v;
  }

  int grp = tid >> 3, ln = tid & 7;
  int h = ht * 32 + grp, bh = b * H_ + h;
  f32x2 Ar2[4], Ai2[4], Bd2[4], Cc2[4];
  DISCRETIZE_PK(h, ln)
  (void)Cc2;
  __syncthreads();   // ut ready

  // ---- state-only local scan (packed fp32) ----
  f32x2 X[4] = {(f32x2){0.f, 0.f}, (f32x2){0.f, 0.f}, (f32x2){0.f, 0.f}, (f32x2){0.f, 0.f}};
#pragma unroll 8
  for (int t = 0; t < LC; ++t) {
    float uu = ut[t][grp];
    f32x2 U2 = (f32x2){uu, uu};
#pragma unroll
    for (int i = 0; i < 4; ++i) {
      f32x2 t1 = pk_mul(Bd2[i], U2);
      f32x2 t2 = pk_fma_swapneg(Ai2[i], X[i], t1);
      X[i] = pk_fma(Ar2[i], X[i], t2);
    }
  }
  float2* dst = xend + ((size_t)bh * NC + c) * 32 + ln * 4;
#pragma unroll
  for (int i = 0; i < 4; ++i) dst[i] = make_float2(X[i].x, X[i].y);
}

// ---------------- scan2: Horner lookback + full scan + butterfly -> yN fp16 (B,L,H) ----------------
// grid (NC, 16, B_) x 256 thr. Kernel boundary = grid-wide sync on xend.
__global__ __launch_bounds__(256) void scan2_k(
    const float* __restrict__ x,
    const float* __restrict__ log_dt,
    const float* __restrict__ log_A_real,
    const float* __restrict__ A_imag,
    const float* __restrict__ B_ri,
    const float* __restrict__ C_ri,
    const float* __restrict__ Dv,
    const float2* __restrict__ xend,
    unsigned short* __restrict__ yN) {
  __shared__ float ut[LC][36];
  __shared__ float ylds[2][8][36];
  int c = blockIdx.x, ht = blockIdx.y, b = blockIdx.z;
  int tid = threadIdx.x;

  // ---- stage u tile [128 t][32 h] ----
#pragma unroll
  for (int i = 0; i < 4; ++i) {
    int r = i * 32 + (tid >> 3);
    int q = tid & 7;
    float4 v = *(const float4*)(x + ((size_t)(b * L_ + c * LC + r) * H_) + ht * 32 + q * 4);
    *(float4*)&ut[r][q * 4] = v;
  }

  int grp = tid >> 3, ln = tid & 7;
  int h = ht * 32 + grp, bh = b * H_ + h;
  f32x2 Ar2[4], Ai2[4], Bd2[4], Cc2[4];
  DISCRETIZE_PK(h, ln)
  float dd8 = Dv[h] * 0.125f;

  // ---- Ad^128 by 7 squarings (scalar, once) ----
  f32x2 Apr2[4], Api2[4];
#pragma unroll
  for (int i = 0; i < 4; ++i) {
    float pr = Ar2[i].x, pi = Ai2[i].x;
#pragma unroll
    for (int s = 0; s < 7; ++s) {
      float qr = pr * pr - pi * pi;
      float qi = 2.0f * pr * pi;
      pr = qr; pi = qi;
    }
    Apr2[i] = (f32x2){pr, pr};
    Api2[i] = (f32x2){pi, pi};
  }

  // ---- lookback: xstart = Horner over xend[c'<c] with Ad^128 (packed) ----
  f32x2 X[4] = {(f32x2){0.f, 0.f}, (f32x2){0.f, 0.f}, (f32x2){0.f, 0.f}, (f32x2){0.f, 0.f}};
  for (int cp = 0; cp < c; ++cp) {
    const float2* e = xend + ((size_t)bh * NC + cp) * 32 + ln * 4;
    float4 e01 = *(const float4*)e;
    float4 e23 = *(const float4*)(e + 2);
    f32x2 E[4] = {(f32x2){e01.x, e01.y}, (f32x2){e01.z, e01.w},
                  (f32x2){e23.x, e23.y}, (f32x2){e23.z, e23.w}};
#pragma unroll
    for (int i = 0; i < 4; ++i) {
      f32x2 t = pk_fma_swapneg(Api2[i], X[i], E[i]);
      X[i] = pk_fma(Apr2[i], X[i], t);
    }
  }
  __syncthreads();   // ut ready

  // ---- full scan + packed C-projection + 8-lane reduce-scatter butterfly ----
#pragma unroll
  for (int w = 0; w < 16; ++w) {
    float v[8];
#define P3STEP(S)                                                            \
    {                                                                        \
      float uu = ut[w * 8 + (S)][grp];                                       \
      f32x2 U2 = (f32x2){uu, uu};                                            \
      f32x2 pacc = (f32x2){0.f, 0.f};                                        \
      _Pragma("unroll")                                                      \
      for (int i = 0; i < 4; ++i) {                                          \
        f32x2 t1 = pk_mul(Bd2[i], U2);                                       \
        f32x2 t2 = pk_fma_swapneg(Ai2[i], X[i], t1);                         \
        X[i] = pk_fma(Ar2[i], X[i], t2);                                     \
        pacc = pk_fma(Cc2[i], X[i], pacc);                                   \
      }                                                                      \
      v[(S)] = fmaf(dd8, uu, pacc.x - pacc.y);                               \
    }
    P3STEP(0) P3STEP(1) P3STEP(2) P3STEP(3)
    P3STEP(4) P3STEP(5) P3STEP(6) P3STEP(7)
#define BFLY(J, M)                                                           \
    {                                                                        \
      bool hi = (ln & (M)) != 0;                                             \
      float snd = hi ? v[(J)] : v[(J) + (M)];                                \
      float rcv = __shfl_xor(snd, (M));                                      \
      float kp = hi ? v[(J) + (M)] : v[(J)];                                 \
      v[(J)] = kp + rcv;                                                     \
    }
    BFLY(0, 4) BFLY(1, 4) BFLY(2, 4) BFLY(3, 4)
    BFLY(0, 2) BFLY(1, 2)
    BFLY(0, 1)
    ylds[w & 1][ln][grp] = v[0];
    __syncthreads();
    int t = tid >> 5;
    int hh = tid & 31;
    float val = ylds[w & 1][t][hh];
    yN[((size_t)b * L_ + c * LC + w * 8 + t) * H_ + ht * 32 + hh] = f2h(val);
    // next window writes the other ylds buffer; no trailing sync needed
  }
}

// ---------------- fused GLU GEMM (fp16 MFMA, single-buffer 32KB -> 5 blocks/CU) ----------------
__global__ __launch_bounds__(256) void glu_gemm_k(const unsigned short* __restrict__ yN,
                                                  const unsigned short* __restrict__ WT1,
                                                  const unsigned short* __restrict__ WT2,
                                                  float* __restrict__ out) {
  __shared__ __align__(16) char lds[32768];   // A:16KB  B1:8KB  B2:8KB
  int tid = threadIdx.x;
  int m0 = blockIdx.x * 128;
  int n0 = blockIdx.y * 64;
  int wave = tid >> 6;
  int lane = tid & 63;
  int wm = wave >> 1;
  int wn = wave & 1;
  int srow = tid >> 3;          // 0..31
  int scb = (tid & 7) * 16;     // col-bytes within 128B row

  f32x4 acc1[4][2], acc2[4][2];
#pragma unroll
  for (int mf = 0; mf < 4; ++mf)
#pragma unroll
    for (int nf = 0; nf < 2; ++nf) {
      f32x4 z; z[0] = 0.f; z[1] = 0.f; z[2] = 0.f; z[3] = 0.f;
      acc1[mf][nf] = z; acc2[mf][nf] = z;
    }

  const char* ybase = (const char*)yN;
  const char* b1base = (const char*)WT1;
  const char* b2base = (const char*)WT2;
  char* As_ = lds;
  char* B1_ = lds + 16384;
  char* B2_ = lds + 24576;

  for (int k0 = 0; k0 < H_; k0 += 64) {
    // stage A [128 m][64 k] + B tiles [64 n][64 k]; linear LDS dest, pre-swizzled src
#pragma unroll
    for (int i = 0; i < 4; ++i) {
      int row = i * 32 + srow;
      int sc = scb ^ ((row & 7) << 4);
      GLD_LDS16(ybase + ((size_t)(m0 + row) * H_ + k0) * 2 + sc, As_ + wave * 1024 + i * 4096);
    }
#pragma unroll
    for (int i = 0; i < 2; ++i) {
      int row = i * 32 + srow;
      int sc = scb ^ ((row & 7) << 4);
      GLD_LDS16(b1base + ((size_t)(n0 + row) * H_ + k0) * 2 + sc, B1_ + wave * 1024 + i * 4096);
      GLD_LDS16(b2base + ((size_t)(n0 + row) * H_ + k0) * 2 + sc, B2_ + wave * 1024 + i * 4096);
    }
    __syncthreads();   // drains gld_lds (vmcnt) per compiler barrier semantics
#pragma unroll
    for (int ks = 0; ks < 2; ++ks) {
      f16x8 a[4], b1[2], b2[2];
      int kb = ks * 64 + (lane >> 4) * 16;
#pragma unroll
      for (int mf = 0; mf < 4; ++mf) {
        int row = wm * 64 + mf * 16 + (lane & 15);
        a[mf] = *(const f16x8*)(As_ + row * 128 + (kb ^ ((row & 7) << 4)));
      }
#pragma unroll
      for (int nf = 0; nf < 2; ++nf) {
        int row = wn * 32 + nf * 16 + (lane & 15);
        int off = row * 128 + (kb ^ ((row & 7) << 4));
        b1[nf] = *(const f16x8*)(B1_ + off);
        b2[nf] = *(const f16x8*)(B2_ + off);
      }
#pragma unroll
      for (int mf = 0; mf < 4; ++mf)
#pragma unroll
        for (int nf = 0; nf < 2; ++nf) {
          acc1[mf][nf] = __builtin_amdgcn_mfma_f32_16x16x32_f16(a[mf], b1[nf], acc1[mf][nf], 0, 0, 0);
          acc2[mf][nf] = __builtin_amdgcn_mfma_f32_16x16x32_f16(a[mf], b2[nf], acc2[mf][nf], 0, 0, 0);
        }
    }
    __syncthreads();   // protect single buffer before next stage
  }
  int nb = n0 + wn * 32 + (lane & 15);
  int rbase = (lane >> 4) * 4;
#pragma unroll
  for (int mf = 0; mf < 4; ++mf)
#pragma unroll
    for (int nf = 0; nf < 2; ++nf)
#pragma unroll
      for (int r = 0; r < 4; ++r) {
        int m = m0 + wm * 64 + mf * 16 + rbase + r;
        float g1 = acc1[mf][nf][r];
        float g2 = acc2[mf][nf][r];
        out[(size_t)m * H_ + nb + nf * 16] = g1 / (1.0f + __expf(-g2));
      }
}

extern "C" void kernel_launch(void* const* d_in, const int* in_sizes, int n_in,
                              void* d_out, int out_size, void* d_ws, size_t ws_size,
                              hipStream_t stream) {
  (void)in_sizes; (void)n_in; (void)out_size; (void)ws_size;
  const float* x          = (const float*)d_in[0];
  const float* log_dt     = (const float*)d_in[1];
  const float* log_A_real = (const float*)d_in[2];
  const float* A_imag     = (const float*)d_in[3];
  const float* B_ri       = (const float*)d_in[4];
  const float* C_ri       = (const float*)d_in[5];
  const float* Dv         = (const float*)d_in[6];
  const float* W1         = (const float*)d_in[7];
  const float* W2         = (const float*)d_in[8];
  float* out = (float*)d_out;
  char* ws = (char*)d_ws;

  unsigned short* yN   = (unsigned short*)(ws);                       // 8 MiB
  float2*         xend = (float2*)(ws + (8u << 20));                  // 8 MiB
  unsigned short* WT1  = (unsigned short*)(ws + (16u << 20));         // 512 KiB
  unsigned short* WT2  = (unsigned short*)(ws + (16u << 20) + (512u << 10));

  scan1_k<<<dim3(NC - 1, 16, B_), 256, 0, stream>>>(
      x, log_dt, log_A_real, A_imag, B_ri, C_ri, W1, W2, WT1, WT2, xend);

  scan2_k<<<dim3(NC, 16, B_), 256, 0, stream>>>(
      x, log_dt, log_A_real, A_imag, B_ri, C_ri, Dv, xend, yN);

  dim3 ggrid((B_ * L_) / 128, H_ / 64);
  glu_gemm_k<<<ggrid, 256, 0, stream>>>(yN, WT1, WT2, out);
}

// Round 11
// 77.263 us; speedup vs baseline: 1.0573x; 1.0573x over previous
//
#include <hip/hip_runtime.h>

#define H_ 512
#define N_ 32
#define B_ 4
#define L_ 2048
#define LC 128
#define NC 16   // L_/LC

typedef _Float16 f16x8 __attribute__((ext_vector_type(8)));
typedef float f32x4 __attribute__((ext_vector_type(4)));
typedef float f32x2 __attribute__((ext_vector_type(2)));

__device__ inline unsigned short f2h(float f) {
  _Float16 h = (_Float16)f;   // RNE
  return __builtin_bit_cast(unsigned short, h);
}

// ---- packed fp32 helpers (VOP3P, 2x rate) ----
__device__ inline f32x2 pk_fma(f32x2 a, f32x2 b, f32x2 c) {
  f32x2 d;
  asm("v_pk_fma_f32 %0, %1, %2, %3" : "=v"(d) : "v"(a), "v"(b), "v"(c));
  return d;
}
// lo = a.lo*(-x.hi) + c.lo ; hi = a.hi*x.lo + c.hi   (complex cross-term)
__device__ inline f32x2 pk_fma_swapneg(f32x2 a, f32x2 x, f32x2 c) {
  f32x2 d;
  asm("v_pk_fma_f32 %0, %1, %2, %3 op_sel:[0,1,0] op_sel_hi:[1,0,1] neg_lo:[0,1,0]"
      : "=v"(d) : "v"(a), "v"(x), "v"(c));
  return d;
}
// lo = a.lo*u.lo ; hi = a.hi*u.lo   (broadcast u.lo; u.hi never read)
__device__ inline f32x2 pk_mul_bl(f32x2 a, f32x2 u) {
  f32x2 d;
  asm("v_pk_mul_f32 %0, %1, %2 op_sel:[0,0] op_sel_hi:[1,0]"
      : "=v"(d) : "v"(a), "v"(u));
  return d;
}

// ---- DPP cross-lane (quad_perm): xor1 = [1,0,3,2] = 0xB1, xor2 = [2,3,0,1] = 0x4E ----
__device__ inline float dpp_xor1(float x) {
  int r = __builtin_amdgcn_update_dpp(0, __builtin_bit_cast(int, x), 0xB1, 0xF, 0xF, true);
  return __builtin_bit_cast(float, r);
}
__device__ inline float dpp_xor2(float x) {
  int r = __builtin_amdgcn_update_dpp(0, __builtin_bit_cast(int, x), 0x4E, 0xF, 0xF, true);
  return __builtin_bit_cast(float, r);
}

#define GLD_LDS16(gsrc, ldst)                                                        \
  __builtin_amdgcn_global_load_lds(                                                  \
      (const __attribute__((address_space(1))) unsigned int*)(gsrc),                 \
      (__attribute__((address_space(3))) unsigned int*)(ldst), 16, 0, 0)

// Inline per-thread discretization: lane ln owns n = ln*4..ln*4+3 of row h.
#define DISCRETIZE_PK(h, ln)                                                         \
  {                                                                                  \
    float dtv = expf(log_dt[(h)]);                                                   \
    _Pragma("unroll")                                                                \
    for (int i = 0; i < 4; ++i) {                                                    \
      int n = (ln) * 4 + i;                                                          \
      int idx = ((h) << 5) + n;                                                      \
      float ar = -expf(log_A_real[idx]);                                             \
      float ai = A_imag[idx];                                                        \
      float dr = 0.5f * dtv * ar, di = 0.5f * dtv * ai;                              \
      float omr = 1.0f - dr;                                                         \
      float inv = 1.0f / (omr * omr + di * di);                                      \
      float adr = (1.0f - dr * dr - di * di) * inv;                                  \
      float adi = 2.0f * di * inv;                                                   \
      float br = B_ri[2 * n], bi = B_ri[2 * n + 1];                                  \
      Ar2[i] = (f32x2){adr, adr};                                                    \
      Ai2[i] = (f32x2){adi, adi};                                                    \
      Bd2[i] = (f32x2){dtv * (br * omr - bi * di) * inv,                             \
                       dtv * (br * di + bi * omr) * inv};                            \
      float2 c = ((const float2*)C_ri)[idx];                                         \
      Cc2[i] = (f32x2){c.x, c.y};                                                    \
    }                                                                                \
  }

// ---------------- scan1: W-transpose prologue + zero-init local chunk scans ----------------
__global__ __launch_bounds__(256) void scan1_k(
    const float* __restrict__ x,
    const float* __restrict__ log_dt,
    const float* __restrict__ log_A_real,
    const float* __restrict__ A_imag,
    const float* __restrict__ B_ri,
    const float* __restrict__ C_ri,
    const float* __restrict__ W1,
    const float* __restrict__ W2,
    unsigned short* __restrict__ WT1,
    unsigned short* __restrict__ WT2,
    float2* __restrict__ xend) {
  __shared__ float ut[LC][36];
  int c = blockIdx.x, ht = blockIdx.y, b = blockIdx.z;
  int tid = threadIdx.x;

  int flat = (b * 16 + ht) * (NC - 1) + c;   // 0..959
  if (flat < 512) {
    float(*tile)[33] = (float(*)[33]) & ut[0][0];   // 4224 B, fits in ut
    const float* W = (flat >> 8) ? W2 : W1;
    unsigned short* WT = (flat >> 8) ? WT2 : WT1;
    int rem = flat & 255;
    int k0 = (rem & 15) << 5, j0 = (rem >> 4) << 5;
    int tx = tid & 31, ty = tid >> 5;
#pragma unroll
    for (int i = 0; i < 32; i += 8)
      tile[ty + i][tx] = W[(size_t)(k0 + ty + i) * H_ + j0 + tx];
    __syncthreads();
#pragma unroll
    for (int i = 0; i < 32; i += 8)
      WT[(size_t)(j0 + ty + i) * H_ + k0 + tx] = f2h(tile[tx][ty + i]);
    __syncthreads();
  }

#pragma unroll
  for (int i = 0; i < 4; ++i) {
    int r = i * 32 + (tid >> 3);
    int q = tid & 7;
    float4 v = *(const float4*)(x + ((size_t)(b * L_ + c * LC + r) * H_) + ht * 32 + q * 4);
    *(float4*)&ut[r][q * 4] = v;
  }

  int grp = tid >> 3, ln = tid & 7;
  int h = ht * 32 + grp, bh = b * H_ + h;
  f32x2 Ar2[4], Ai2[4], Bd2[4], Cc2[4];
  DISCRETIZE_PK(h, ln)
  (void)Cc2;
  __syncthreads();   // ut ready

  f32x2 X[4] = {(f32x2){0.f, 0.f}, (f32x2){0.f, 0.f}, (f32x2){0.f, 0.f}, (f32x2){0.f, 0.f}};
#pragma unroll 8
  for (int t = 0; t < LC; ++t) {
    f32x2 U;
    U.x = ut[t][grp];
#pragma unroll
    for (int i = 0; i < 4; ++i) {
      f32x2 t1 = pk_mul_bl(Bd2[i], U);
      f32x2 t2 = pk_fma_swapneg(Ai2[i], X[i], t1);
      X[i] = pk_fma(Ar2[i], X[i], t2);
    }
  }
  float2* dst = xend + ((size_t)bh * NC + c) * 32 + ln * 4;
#pragma unroll
  for (int i = 0; i < 4; ++i) dst[i] = make_float2(X[i].x, X[i].y);
}

// ---------------- scan2: lookback + full scan + DPP butterfly + direct scatter stores ----------------
// grid (NC, 16, B_) x 256 thr. No in-loop barriers.
__global__ __launch_bounds__(256) void scan2_k(
    const float* __restrict__ x,
    const float* __restrict__ log_dt,
    const float* __restrict__ log_A_real,
    const float* __restrict__ A_imag,
    const float* __restrict__ B_ri,
    const float* __restrict__ C_ri,
    const float* __restrict__ Dv,
    const float2* __restrict__ xend,
    unsigned short* __restrict__ yN) {
  __shared__ float ut[LC][36];
  int c = blockIdx.x, ht = blockIdx.y, b = blockIdx.z;
  int tid = threadIdx.x;

#pragma unroll
  for (int i = 0; i < 4; ++i) {
    int r = i * 32 + (tid >> 3);
    int q = tid & 7;
    float4 v = *(const float4*)(x + ((size_t)(b * L_ + c * LC + r) * H_) + ht * 32 + q * 4);
    *(float4*)&ut[r][q * 4] = v;
  }

  int grp = tid >> 3, ln = tid & 7;
  int h = ht * 32 + grp, bh = b * H_ + h;
  f32x2 Ar2[4], Ai2[4], Bd2[4], Cc2[4];
  DISCRETIZE_PK(h, ln)
  float dd8 = Dv[h] * 0.125f;

  // Ad^128 by 7 squarings
  f32x2 Apr2[4], Api2[4];
#pragma unroll
  for (int i = 0; i < 4; ++i) {
    float pr = Ar2[i].x, pi = Ai2[i].x;
#pragma unroll
    for (int s = 0; s < 7; ++s) {
      float qr = pr * pr - pi * pi;
      float qi = 2.0f * pr * pi;
      pr = qr; pi = qi;
    }
    Apr2[i] = (f32x2){pr, pr};
    Api2[i] = (f32x2){pi, pi};
  }

  // lookback: Horner over xend[c'<c] with Ad^128 (packed)
  f32x2 X[4] = {(f32x2){0.f, 0.f}, (f32x2){0.f, 0.f}, (f32x2){0.f, 0.f}, (f32x2){0.f, 0.f}};
  for (int cp = 0; cp < c; ++cp) {
    const float2* e = xend + ((size_t)bh * NC + cp) * 32 + ln * 4;
    float4 e01 = *(const float4*)e;
    float4 e23 = *(const float4*)(e + 2);
    f32x2 E[4] = {(f32x2){e01.x, e01.y}, (f32x2){e01.z, e01.w},
                  (f32x2){e23.x, e23.y}, (f32x2){e23.z, e23.w}};
#pragma unroll
    for (int i = 0; i < 4; ++i) {
      f32x2 t = pk_fma_swapneg(Api2[i], X[i], E[i]);
      X[i] = pk_fma(Apr2[i], X[i], t);
    }
  }
  __syncthreads();   // ut ready (only barrier in the kernel)

  unsigned short* yb = yN + ((size_t)b * L_ + c * LC + ln) * H_ + h;

#pragma unroll
  for (int w = 0; w < 16; ++w) {
    float v[8];
#define P3STEP(S)                                                            \
    {                                                                        \
      f32x2 U;                                                               \
      U.x = ut[w * 8 + (S)][grp];                                            \
      f32x2 pacc = (f32x2){0.f, 0.f};                                        \
      _Pragma("unroll")                                                      \
      for (int i = 0; i < 4; ++i) {                                          \
        f32x2 t1 = pk_mul_bl(Bd2[i], U);                                     \
        f32x2 t2 = pk_fma_swapneg(Ai2[i], X[i], t1);                         \
        X[i] = pk_fma(Ar2[i], X[i], t2);                                     \
        pacc = pk_fma(Cc2[i], X[i], pacc);                                   \
      }                                                                      \
      v[(S)] = fmaf(dd8, U.x, pacc.x - pacc.y);                              \
    }
    P3STEP(0) P3STEP(1) P3STEP(2) P3STEP(3)
    P3STEP(4) P3STEP(5) P3STEP(6) P3STEP(7)
    // reduce-scatter butterfly, stages 1,2 via DPP quad_perm, stage 4 via shfl
#define BFLY1(J)                                                             \
    {                                                                        \
      bool hi = (ln & 1) != 0;                                               \
      float snd = hi ? v[(J)] : v[(J) + 1];                                  \
      float rcv = dpp_xor1(snd);                                             \
      float kp = hi ? v[(J) + 1] : v[(J)];                                   \
      v[(J)] = kp + rcv;                                                     \
    }
#define BFLY2(J)                                                             \
    {                                                                        \
      bool hi = (ln & 2) != 0;                                               \
      float snd = hi ? v[(J)] : v[(J) + 2];                                  \
      float rcv = dpp_xor2(snd);                                             \
      float kp = hi ? v[(J) + 2] : v[(J)];                                   \
      v[(J)] = kp + rcv;                                                     \
    }
    BFLY1(0) BFLY1(2) BFLY1(4) BFLY1(6)
    BFLY2(0) BFLY2(4)
    {
      bool hi = (ln & 4) != 0;
      float snd = hi ? v[0] : v[4];
      float rcv = __shfl_xor(snd, 4);
      float kp = hi ? v[4] : v[0];
      v[0] = kp + rcv;
    }
    // lane ln holds y[t = c*128 + w*8 + ln] for this h; direct scatter store
    yb[(size_t)w * 8 * H_] = f2h(v[0]);
  }
}

// ---------------- fused GLU GEMM (fp16 MFMA, single-buffer 32KB) ----------------
__global__ __launch_bounds__(256) void glu_gemm_k(const unsigned short* __restrict__ yN,
                                                  const unsigned short* __restrict__ WT1,
                                                  const unsigned short* __restrict__ WT2,
                                                  float* __restrict__ out) {
  __shared__ __align__(16) char lds[32768];   // A:16KB  B1:8KB  B2:8KB
  int tid = threadIdx.x;
  int m0 = blockIdx.x * 128;
  int n0 = blockIdx.y * 64;
  int wave = tid >> 6;
  int lane = tid & 63;
  int wm = wave >> 1;
  int wn = wave & 1;
  int srow = tid >> 3;          // 0..31
  int scb = (tid & 7) * 16;     // col-bytes within 128B row

  f32x4 acc1[4][2], acc2[4][2];
#pragma unroll
  for (int mf = 0; mf < 4; ++mf)
#pragma unroll
    for (int nf = 0; nf < 2; ++nf) {
      f32x4 z; z[0] = 0.f; z[1] = 0.f; z[2] = 0.f; z[3] = 0.f;
      acc1[mf][nf] = z; acc2[mf][nf] = z;
    }

  const char* ybase = (const char*)yN;
  const char* b1base = (const char*)WT1;
  const char* b2base = (const char*)WT2;
  char* As_ = lds;
  char* B1_ = lds + 16384;
  char* B2_ = lds + 24576;

  for (int k0 = 0; k0 < H_; k0 += 64) {
#pragma unroll
    for (int i = 0; i < 4; ++i) {
      int row = i * 32 + srow;
      int sc = scb ^ ((row & 7) << 4);
      GLD_LDS16(ybase + ((size_t)(m0 + row) * H_ + k0) * 2 + sc, As_ + wave * 1024 + i * 4096);
    }
#pragma unroll
    for (int i = 0; i < 2; ++i) {
      int row = i * 32 + srow;
      int sc = scb ^ ((row & 7) << 4);
      GLD_LDS16(b1base + ((size_t)(n0 + row) * H_ + k0) * 2 + sc, B1_ + wave * 1024 + i * 4096);
      GLD_LDS16(b2base + ((size_t)(n0 + row) * H_ + k0) * 2 + sc, B2_ + wave * 1024 + i * 4096);
    }
    __syncthreads();
#pragma unroll
    for (int ks = 0; ks < 2; ++ks) {
      f16x8 a[4], b1[2], b2[2];
      int kb = ks * 64 + (lane >> 4) * 16;
#pragma unroll
      for (int mf = 0; mf < 4; ++mf) {
        int row = wm * 64 + mf * 16 + (lane & 15);
        a[mf] = *(const f16x8*)(As_ + row * 128 + (kb ^ ((row & 7) << 4)));
      }
#pragma unroll
      for (int nf = 0; nf < 2; ++nf) {
        int row = wn * 32 + nf * 16 + (lane & 15);
        int off = row * 128 + (kb ^ ((row & 7) << 4));
        b1[nf] = *(const f16x8*)(B1_ + off);
        b2[nf] = *(const f16x8*)(B2_ + off);
      }
#pragma unroll
      for (int mf = 0; mf < 4; ++mf)
#pragma unroll
        for (int nf = 0; nf < 2; ++nf) {
          acc1[mf][nf] = __builtin_amdgcn_mfma_f32_16x16x32_f16(a[mf], b1[nf], acc1[mf][nf], 0, 0, 0);
          acc2[mf][nf] = __builtin_amdgcn_mfma_f32_16x16x32_f16(a[mf], b2[nf], acc2[mf][nf], 0, 0, 0);
        }
    }
    __syncthreads();
  }
  int nb = n0 + wn * 32 + (lane & 15);
  int rbase = (lane >> 4) * 4;
#pragma unroll
  for (int mf = 0; mf < 4; ++mf)
#pragma unroll
    for (int nf = 0; nf < 2; ++nf)
#pragma unroll
      for (int r = 0; r < 4; ++r) {
        int m = m0 + wm * 64 + mf * 16 + rbase + r;
        float g1 = acc1[mf][nf][r];
        float g2 = acc2[mf][nf][r];
        out[(size_t)m * H_ + nb + nf * 16] = g1 / (1.0f + __expf(-g2));
      }
}

extern "C" void kernel_launch(void* const* d_in, const int* in_sizes, int n_in,
                              void* d_out, int out_size, void* d_ws, size_t ws_size,
                              hipStream_t stream) {
  (void)in_sizes; (void)n_in; (void)out_size; (void)ws_size;
  const float* x          = (const float*)d_in[0];
  const float* log_dt     = (const float*)d_in[1];
  const float* log_A_real = (const float*)d_in[2];
  const float* A_imag     = (const float*)d_in[3];
  const float* B_ri       = (const float*)d_in[4];
  const float* C_ri       = (const float*)d_in[5];
  const float* Dv         = (const float*)d_in[6];
  const float* W1         = (const float*)d_in[7];
  const float* W2         = (const float*)d_in[8];
  float* out = (float*)d_out;
  char* ws = (char*)d_ws;

  unsigned short* yN   = (unsigned short*)(ws);                       // 8 MiB
  float2*         xend = (float2*)(ws + (8u << 20));                  // 8 MiB
  unsigned short* WT1  = (unsigned short*)(ws + (16u << 20));         // 512 KiB
  unsigned short* WT2  = (unsigned short*)(ws + (16u << 20) + (512u << 10));

  scan1_k<<<dim3(NC - 1, 16, B_), 256, 0, stream>>>(
      x, log_dt, log_A_real, A_imag, B_ri, C_ri, W1, W2, WT1, WT2, xend);

  scan2_k<<<dim3(NC, 16, B_), 256, 0, stream>>>(
      x, log_dt, log_A_real, A_imag, B_ri, C_ri, Dv, xend, yN);

  dim3 ggrid((B_ * L_) / 128, H_ / 64);
  glu_gemm_k<<<ggrid, 256, 0, stream>>>(yN, WT1, WT2, out);
}